// Round 6
// baseline (151.289 us; speedup 1.0000x reference)
//
#include <hip/hip_runtime.h>

#define Bn 4
#define Qn 1024
#define Kn 1024
#define Dd 256
#define Hh 64
#define Dv 256
#define TQ 16
#define SCP 1028   // sc row stride in floats (4112 B/row = 2056 shorts)

typedef __attribute__((ext_vector_type(8))) short short8;
typedef __attribute__((ext_vector_type(4))) float floatx4;

__device__ __forceinline__ short f32_to_bf16(float x) {
    unsigned u = __float_as_uint(x);
    unsigned r = u + 0x7fffu + ((u >> 16) & 1u);   // RNE
    return (short)(r >> 16);
}
__device__ __forceinline__ float bf16_to_f32(short h) {
    return __uint_as_float(((unsigned)(unsigned short)h) << 16);
}

// Fused prep:
//  blocks 0..255   : projections, 32 rows each. X-tile staged in LDS via
//                    coalesced float4 loads (fixes the wave-uniform-load
//                    serialization that made proj ~55us); W read from L1/L2
//                    coalesced; X re-read from LDS as uniform broadcasts.
//  blocks 256..383 : V -> split-bf16 MFMA-A-fragment swizzle.
__global__ __launch_bounds__(256) void prep_kernel(const float* __restrict__ Xq,
                                                   const float* __restrict__ Wq,
                                                   const float* __restrict__ Xk,
                                                   const float* __restrict__ Wk,
                                                   const float* __restrict__ V,
                                                   float* __restrict__ Eq,
                                                   float* __restrict__ Ekt,
                                                   short* __restrict__ Vhi,
                                                   short* __restrict__ Vlo) {
    __shared__ __align__(16) float lds[32 * 261];   // proj uses 32*256 of it
    int t = threadIdx.x;
    if (blockIdx.x < 256) {
        // ---- projection ----
        int side = blockIdx.x >> 7;                  // 0: q, 1: k
        int row0 = (blockIdx.x & 127) * 32;          // local 32-row chunk
        const float* X = (side ? Xk : Xq) + (size_t)row0 * Dd;
        const float* W = side ? Wk : Wq;

        #pragma unroll
        for (int j = 0; j < 8; ++j)                  // coalesced stage: 32x256 f32
            ((float4*)lds)[t + j * 256] = ((const float4*)X)[t + j * 256];
        __syncthreads();

        int h = t & 63, wv = t >> 6;
        float acc[8] = {0.f, 0.f, 0.f, 0.f, 0.f, 0.f, 0.f, 0.f};
        #pragma unroll 8
        for (int d4 = 0; d4 < Dd / 4; ++d4) {
            float w0 = W[(d4 * 4 + 0) * Hh + h];     // coalesced, L1/L2-hot
            float w1 = W[(d4 * 4 + 1) * Hh + h];
            float w2 = W[(d4 * 4 + 2) * Hh + h];
            float w3 = W[(d4 * 4 + 3) * Hh + h];
            #pragma unroll
            for (int r = 0; r < 8; ++r) {
                float4 xv = ((const float4*)lds)[(wv * 8 + r) * 64 + d4]; // bcast
                acc[r] = fmaf(xv.x, w0, acc[r]);
                acc[r] = fmaf(xv.y, w1, acc[r]);
                acc[r] = fmaf(xv.z, w2, acc[r]);
                acc[r] = fmaf(xv.w, w3, acc[r]);
            }
        }
        #pragma unroll
        for (int r = 0; r < 8; ++r) {
            int gr = row0 + wv * 8 + r;
            float e = __expf(2.f * acc[r]);
            if (!side) {
                Eq[gr * Hh + h] = e;
            } else {
                int b = gr >> 10, k = gr & 1023;
                Ekt[(b * Hh + h) * Kn + k] = e;
            }
        }
    } else {
        // ---- V prep: swizzle into exact MFMA A-fragment order, hi+lo bf16 ----
        int blk = blockIdx.x - 256;
        int b = blk >> 5;
        int kt = blk & 31;
        const float* Vg = V + (b * Kn + kt * 32) * Dv;
        for (int i = 0; i < 8; ++i) {
            int k = i * 4 + (t >> 6);
            int n4 = (t & 63) * 4;
            float4 v = *(const float4*)(Vg + k * Dv + n4);
            lds[k * 261 + n4 + 0] = v.x;
            lds[k * 261 + n4 + 1] = v.y;
            lds[k * 261 + n4 + 2] = v.z;
            lds[k * 261 + n4 + 3] = v.w;
        }
        __syncthreads();
        int wave = t >> 6, l = t & 63;
        int n_in = l & 15, kc = l >> 4;
        for (int p = 0; p < 4; ++p) {
            int nt = wave * 4 + p;
            int n = nt * 16 + n_in;
            short8 hi, lo;
            #pragma unroll
            for (int j = 0; j < 8; ++j) {
                float x = lds[(kc * 8 + j) * 261 + n];
                short hs = f32_to_bf16(x);
                hi[j] = hs;
                lo[j] = f32_to_bf16(x - bf16_to_f32(hs));
            }
            size_t base = (((size_t)(b * 32 + kt) * 16 + nt) * 512) + (size_t)l * 8;
            *(short8*)(Vhi + base) = hi;
            *(short8*)(Vlo + base) = lo;
        }
    }
}

// score(q,k) = W_sum - 2*sum_h w_h/(Eq_h*Ek_h+1); W_sum cancels in softmax.
// Pairwise rcp: w1/a + w2/b = (w1*b + w2*a)*rcp(a*b).  P -> bf16 hi/lo in
// place over sc, AV via mfma_f32_16x16x32_bf16 split precision.
// 1024 threads/block (16 waves/CU) for latency hiding at 256 blocks.
__global__ __launch_bounds__(1024) void attn_kernel(const float* __restrict__ Eq,
                                                    const float* __restrict__ Ekt,
                                                    const short* __restrict__ Vhi,
                                                    const short* __restrict__ Vlo,
                                                    const float* __restrict__ wv,
                                                    float* __restrict__ out) {
    __shared__ __align__(16) float sc[TQ * SCP];       // 65.8 KB, reused as P hi/lo
    __shared__ __align__(16) float4 qp4[TQ * (Hh / 4)];// 4 KB
    __shared__ __align__(16) float wv_s[Hh];
    __shared__ float rinv_s[TQ];

    int tid = threadIdx.x;
    int b = blockIdx.x >> 6;                 // 64 q-tiles per batch
    int qbase = (blockIdx.x & 63) * TQ;

    const float* qrow = Eq + (b * Qn + qbase) * Hh;
    ((float*)qp4)[tid] = qrow[tid];          // 1024 = TQ*Hh
    if (tid < Hh) wv_s[tid] = wv[tid];
    __syncthreads();

    // ---- score phase: thread owns k = tid ----
    const float* kb = Ekt + b * Hh * Kn;
    float s[TQ];
    #pragma unroll
    for (int q = 0; q < TQ; ++q) s[q] = 0.f;

    for (int h4 = 0; h4 < Hh / 4; ++h4) {
        float4 w4 = ((const float4*)wv_s)[h4];
        const float* kh = kb + h4 * 4 * Kn;
        float e0 = kh[0 * Kn + tid];
        float e1 = kh[1 * Kn + tid];
        float e2 = kh[2 * Kn + tid];
        float e3 = kh[3 * Kn + tid];
        #pragma unroll 4
        for (int q = 0; q < TQ; ++q) {
            float4 qv = qp4[q * (Hh / 4) + h4];          // LDS b128 broadcast
            float a  = fmaf(qv.x, e0, 1.f);
            float bb = fmaf(qv.y, e1, 1.f);
            float c  = fmaf(qv.z, e2, 1.f);
            float d  = fmaf(qv.w, e3, 1.f);
            float nab = fmaf(w4.x, bb, w4.y * a);
            float ncd = fmaf(w4.z, d, w4.w * c);
            s[q] = fmaf(nab, __builtin_amdgcn_rcpf(a * bb), s[q]);
            s[q] = fmaf(ncd, __builtin_amdgcn_rcpf(c * d), s[q]);
        }
    }
    #pragma unroll
    for (int q = 0; q < TQ; ++q) sc[q * SCP + tid] = s[q];
    __syncthreads();

    // ---- softmax over -2*s: wave w handles row w ----
    int wave = tid >> 6, lane = tid & 63;
    {
        int q = wave;
        float m = 1e30f;
        for (int i = lane; i < Kn; i += 64) m = fminf(m, sc[q * SCP + i]);
        #pragma unroll
        for (int off = 32; off >= 1; off >>= 1) m = fminf(m, __shfl_xor(m, off, 64));
        float sum = 0.f;
        for (int i = lane; i < Kn; i += 64) {
            float e = __expf(2.f * (m - sc[q * SCP + i]));
            sc[q * SCP + i] = e;
            sum += e;
        }
        #pragma unroll
        for (int off = 32; off >= 1; off >>= 1) sum += __shfl_xor(sum, off, 64);
        if (lane == 0) rinv_s[q] = 1.f / sum;
    }
    __syncthreads();

    // ---- in-place convert P -> bf16 hi/lo over sc's own bytes ----
    // Row q: hi shorts at short-idx q*2056 + k, lo at q*2056 + 1024 + k.
    {
        int q = wave;
        float x[16];
        #pragma unroll
        for (int j = 0; j < 16; ++j) x[j] = sc[q * SCP + lane + 64 * j];
        __syncthreads();
        short* sp = (short*)sc;
        #pragma unroll
        for (int j = 0; j < 16; ++j) {
            int k = lane + 64 * j;
            short hs = f32_to_bf16(x[j]);
            sp[q * 2056 + k] = hs;
            sp[q * 2056 + 1024 + k] = f32_to_bf16(x[j] - bf16_to_f32(hs));
        }
    }
    __syncthreads();

    // ---- AV via MFMA: wave owns ntile = wave ----
    int qf = lane & 15, kc = lane >> 4;
    floatx4 acc = {0.f, 0.f, 0.f, 0.f};
    const char* scb = (const char*)sc;
    for (int kt = 0; kt < 32; ++kt) {
        short8 bhi = *(const short8*)(scb + qf * 4112 + kt * 64 + kc * 16);
        short8 blo = *(const short8*)(scb + qf * 4112 + 2048 + kt * 64 + kc * 16);
        size_t base = (((size_t)(b * 32 + kt) * 16 + wave) * 512) + (size_t)lane * 8;
        short8 ah = *(const short8*)(Vhi + base);
        short8 al = *(const short8*)(Vlo + base);
        acc = __builtin_amdgcn_mfma_f32_16x16x32_bf16(ah, bhi, acc, 0, 0, 0);
        acc = __builtin_amdgcn_mfma_f32_16x16x32_bf16(al, bhi, acc, 0, 0, 0);
        acc = __builtin_amdgcn_mfma_f32_16x16x32_bf16(ah, blo, acc, 0, 0, 0);
    }
    {
        float r = rinv_s[qf];
        float* ob = out + ((size_t)(b * Qn + qbase + qf)) * Dv + wave * 16 + kc * 4;
        float4 o = { acc[0] * r, acc[1] * r, acc[2] * r, acc[3] * r };
        *(float4*)ob = o;
    }
}

extern "C" void kernel_launch(void* const* d_in, const int* in_sizes, int n_in,
                              void* d_out, int out_size, void* d_ws, size_t ws_size,
                              hipStream_t stream) {
    const float* queries = (const float*)d_in[0];
    const float* keys    = (const float*)d_in[1];
    const float* values  = (const float*)d_in[2];
    const float* W_q     = (const float*)d_in[3];
    const float* W_k     = (const float*)d_in[4];
    const float* w_v     = (const float*)d_in[5];
    float* out = (float*)d_out;

    float* Eq  = (float*)d_ws;                 // [B*Q, H]      1 MB
    float* Ekt = Eq + Bn * Qn * Hh;            // [B, H, K]     1 MB
    short* Vhi = (short*)(Ekt + Bn * Kn * Hh); // frag-order    2 MB
    short* Vlo = Vhi + (size_t)Bn * Kn * Dv;   // frag-order    2 MB

    prep_kernel<<<384, 256, 0, stream>>>(queries, W_q, keys, W_k, values,
                                         Eq, Ekt, Vhi, Vlo);
    attn_kernel<<<Bn * (Qn / TQ), 1024, 0, stream>>>(Eq, Ekt, Vhi, Vlo, w_v, out);
}

// Round 7
// 141.104 us; speedup vs baseline: 1.0722x; 1.0722x over previous
//
#include <hip/hip_runtime.h>

#define Bn 4
#define Qn 1024
#define Kn 1024
#define Dd 256
#define Hh 64
#define Dv 256
#define TQ 8
#define SCP 1028   // sc row stride in floats (4112 B/row = 2056 shorts)

typedef __attribute__((ext_vector_type(8))) short short8;
typedef __attribute__((ext_vector_type(4))) float floatx4;

__device__ __forceinline__ short f32_to_bf16(float x) {
    unsigned u = __float_as_uint(x);
    unsigned r = u + 0x7fffu + ((u >> 16) & 1u);   // RNE
    return (short)(r >> 16);
}
__device__ __forceinline__ float bf16_to_f32(short h) {
    return __uint_as_float(((unsigned)(unsigned short)h) << 16);
}

// Fused prep (R5 structure — best measured residual):
//  blocks 0..511  : projections (Eq + transposed Ekt, exp-folded), 4 rows/wave
//  blocks 512..639: V -> split-bf16 MFMA-A-fragment swizzle
__global__ __launch_bounds__(256) void prep_kernel(const float* __restrict__ Xq,
                                                   const float* __restrict__ Wq,
                                                   const float* __restrict__ Xk,
                                                   const float* __restrict__ Wk,
                                                   const float* __restrict__ V,
                                                   float* __restrict__ Eq,
                                                   float* __restrict__ Ekt,
                                                   short* __restrict__ Vhi,
                                                   short* __restrict__ Vlo) {
    __shared__ float tile[32 * 261];
    int t = threadIdx.x;
    if (blockIdx.x < 512) {
        int gw = blockIdx.x * 4 + (t >> 6);
        int h = t & 63;
        int side = gw >> 10;
        int row0 = (gw & 1023) * 4;
        const float* X = side ? Xk : Xq;
        const float* W = side ? Wk : Wq;
        float acc[4] = {0.f, 0.f, 0.f, 0.f};
        for (int d4 = 0; d4 < Dd / 4; ++d4) {
            float w0 = W[(d4 * 4 + 0) * Hh + h];
            float w1 = W[(d4 * 4 + 1) * Hh + h];
            float w2 = W[(d4 * 4 + 2) * Hh + h];
            float w3 = W[(d4 * 4 + 3) * Hh + h];
            #pragma unroll
            for (int r = 0; r < 4; ++r) {
                float4 xv = ((const float4*)(X + (row0 + r) * Dd))[d4];
                acc[r] = fmaf(xv.x, w0, acc[r]);
                acc[r] = fmaf(xv.y, w1, acc[r]);
                acc[r] = fmaf(xv.z, w2, acc[r]);
                acc[r] = fmaf(xv.w, w3, acc[r]);
            }
        }
        #pragma unroll
        for (int r = 0; r < 4; ++r) {
            int row = row0 + r;
            float e = __expf(2.f * acc[r]);
            if (!side) {
                Eq[row * Hh + h] = e;
            } else {
                int b = row >> 10, k = row & 1023;
                Ekt[(b * Hh + h) * Kn + k] = e;
            }
        }
    } else {
        int blk = blockIdx.x - 512;
        int b = blk >> 5;
        int kt = blk & 31;
        const float* Vg = V + (b * Kn + kt * 32) * Dv;
        for (int i = 0; i < 8; ++i) {
            int k = i * 4 + (t >> 6);
            int n4 = (t & 63) * 4;
            float4 v = *(const float4*)(Vg + k * Dv + n4);
            tile[k * 261 + n4 + 0] = v.x;
            tile[k * 261 + n4 + 1] = v.y;
            tile[k * 261 + n4 + 2] = v.z;
            tile[k * 261 + n4 + 3] = v.w;
        }
        __syncthreads();
        int wave = t >> 6, l = t & 63;
        int n_in = l & 15, kc = l >> 4;
        for (int p = 0; p < 4; ++p) {
            int nt = wave * 4 + p;
            int n = nt * 16 + n_in;
            short8 hi, lo;
            #pragma unroll
            for (int j = 0; j < 8; ++j) {
                float x = tile[(kc * 8 + j) * 261 + n];
                short hs = f32_to_bf16(x);
                hi[j] = hs;
                lo[j] = f32_to_bf16(x - bf16_to_f32(hs));
            }
            size_t base = (((size_t)(b * 32 + kt) * 16 + nt) * 512) + (size_t)l * 8;
            *(short8*)(Vhi + base) = hi;
            *(short8*)(Vlo + base) = lo;
        }
    }
}

// score(q,k) = W_sum - 2*sum_h w_h/(Eq_h*Ek_h+1); W_sum cancels in softmax.
// Pairwise rcp: w1/a + w2/b = (w1*b + w2*a)*rcp(a*b).  P -> bf16 hi/lo in
// place over sc, AV via mfma_f32_16x16x32_bf16 split precision.
// TQ=8 / 512 threads / 512 blocks: 2 blocks/CU co-resident (35 KB LDS),
// ~52 VGPR (no accumulator spill — 1024-thr variant starved registers, R6).
__global__ __launch_bounds__(512) void attn_kernel(const float* __restrict__ Eq,
                                                   const float* __restrict__ Ekt,
                                                   const short* __restrict__ Vhi,
                                                   const short* __restrict__ Vlo,
                                                   const float* __restrict__ wv,
                                                   float* __restrict__ out) {
    __shared__ __align__(16) float sc[TQ * SCP];       // 32.9 KB, reused as P hi/lo
    __shared__ __align__(16) float4 qp4[TQ * (Hh / 4)];// 2 KB
    __shared__ __align__(16) float wv_s[Hh];
    __shared__ float rinv_s[TQ];

    int tid = threadIdx.x;
    int b = blockIdx.x >> 7;                 // 128 q-tiles per batch
    int qbase = (blockIdx.x & 127) * TQ;

    const float* qrow = Eq + (b * Qn + qbase) * Hh;
    ((float*)qp4)[tid] = qrow[tid];          // 512 = TQ*Hh
    if (tid < Hh) wv_s[tid] = wv[tid];
    __syncthreads();

    // ---- score phase: thread owns k = tid + 512*j ----
    const float* kb = Ekt + b * Hh * Kn;
    float s[TQ][2];
    #pragma unroll
    for (int q = 0; q < TQ; ++q) { s[q][0] = 0.f; s[q][1] = 0.f; }

    for (int h4 = 0; h4 < Hh / 4; ++h4) {
        float4 w4 = ((const float4*)wv_s)[h4];
        const float* kh = kb + h4 * 4 * Kn;
        float e0[2], e1[2], e2[2], e3[2];
        #pragma unroll
        for (int j = 0; j < 2; ++j) {
            int k = tid + j * 512;
            e0[j] = kh[0 * Kn + k];
            e1[j] = kh[1 * Kn + k];
            e2[j] = kh[2 * Kn + k];
            e3[j] = kh[3 * Kn + k];
        }
        #pragma unroll 4
        for (int q = 0; q < TQ; ++q) {
            float4 qv = qp4[q * (Hh / 4) + h4];          // LDS b128 broadcast
            #pragma unroll
            for (int j = 0; j < 2; ++j) {
                float a  = fmaf(qv.x, e0[j], 1.f);
                float bb = fmaf(qv.y, e1[j], 1.f);
                float c  = fmaf(qv.z, e2[j], 1.f);
                float d  = fmaf(qv.w, e3[j], 1.f);
                float nab = fmaf(w4.x, bb, w4.y * a);
                float ncd = fmaf(w4.z, d, w4.w * c);
                s[q][j] = fmaf(nab, __builtin_amdgcn_rcpf(a * bb), s[q][j]);
                s[q][j] = fmaf(ncd, __builtin_amdgcn_rcpf(c * d), s[q][j]);
            }
        }
    }
    #pragma unroll
    for (int j = 0; j < 2; ++j)
        #pragma unroll
        for (int q = 0; q < TQ; ++q) sc[q * SCP + tid + j * 512] = s[q][j];
    __syncthreads();

    // ---- softmax over -2*s: wave w handles row q=w ----
    int wave = tid >> 6, lane = tid & 63;
    {
        int q = wave;
        float m = 1e30f;
        for (int i = lane; i < Kn; i += 64) m = fminf(m, sc[q * SCP + i]);
        #pragma unroll
        for (int off = 32; off >= 1; off >>= 1) m = fminf(m, __shfl_xor(m, off, 64));
        float sum = 0.f;
        for (int i = lane; i < Kn; i += 64) {
            float e = __expf(2.f * (m - sc[q * SCP + i]));
            sc[q * SCP + i] = e;
            sum += e;
        }
        #pragma unroll
        for (int off = 32; off >= 1; off >>= 1) sum += __shfl_xor(sum, off, 64);
        if (lane == 0) rinv_s[q] = 1.f / sum;
    }
    __syncthreads();

    // ---- in-place convert P -> bf16 hi/lo over sc's own bytes ----
    // Row q: hi shorts at short-idx q*2056 + k, lo at q*2056 + 1024 + k.
    {
        int q = wave;
        float x[16];
        #pragma unroll
        for (int j = 0; j < 16; ++j) x[j] = sc[q * SCP + lane + 64 * j];
        __syncthreads();
        short* sp = (short*)sc;
        #pragma unroll
        for (int j = 0; j < 16; ++j) {
            int k = lane + 64 * j;
            short hs = f32_to_bf16(x[j]);
            sp[q * 2056 + k] = hs;
            sp[q * 2056 + 1024 + k] = f32_to_bf16(x[j] - bf16_to_f32(hs));
        }
    }
    __syncthreads();

    // ---- AV via MFMA: wave owns ntiles {2w, 2w+1}; q-cols 8..15 masked ----
    int qf = lane & 15, kc = lane >> 4;
    int q8 = qf & 7;
    bool qok = qf < TQ;
    floatx4 acc0 = {0.f, 0.f, 0.f, 0.f};
    floatx4 acc1 = {0.f, 0.f, 0.f, 0.f};
    short8 z8 = (short8)(short)0;
    const char* scb = (const char*)sc;
    for (int kt = 0; kt < 32; ++kt) {
        short8 bhi = *(const short8*)(scb + q8 * 4112 + kt * 64 + kc * 16);
        short8 blo = *(const short8*)(scb + q8 * 4112 + 2048 + kt * 64 + kc * 16);
        if (!qok) { bhi = z8; blo = z8; }
        size_t base0 = (((size_t)(b * 32 + kt) * 16 + wave * 2 + 0) * 512) + (size_t)lane * 8;
        size_t base1 = (((size_t)(b * 32 + kt) * 16 + wave * 2 + 1) * 512) + (size_t)lane * 8;
        short8 a0h = *(const short8*)(Vhi + base0);
        short8 a0l = *(const short8*)(Vlo + base0);
        short8 a1h = *(const short8*)(Vhi + base1);
        short8 a1l = *(const short8*)(Vlo + base1);
        acc0 = __builtin_amdgcn_mfma_f32_16x16x32_bf16(a0h, bhi, acc0, 0, 0, 0);
        acc0 = __builtin_amdgcn_mfma_f32_16x16x32_bf16(a0l, bhi, acc0, 0, 0, 0);
        acc0 = __builtin_amdgcn_mfma_f32_16x16x32_bf16(a0h, blo, acc0, 0, 0, 0);
        acc1 = __builtin_amdgcn_mfma_f32_16x16x32_bf16(a1h, bhi, acc1, 0, 0, 0);
        acc1 = __builtin_amdgcn_mfma_f32_16x16x32_bf16(a1l, bhi, acc1, 0, 0, 0);
        acc1 = __builtin_amdgcn_mfma_f32_16x16x32_bf16(a1h, blo, acc1, 0, 0, 0);
    }
    if (qok) {
        float r = rinv_s[q8];
        float* ob = out + ((size_t)(b * Qn + qbase + q8)) * Dv + wave * 32 + kc * 4;
        float4 o0 = { acc0[0] * r, acc0[1] * r, acc0[2] * r, acc0[3] * r };
        float4 o1 = { acc1[0] * r, acc1[1] * r, acc1[2] * r, acc1[3] * r };
        *(float4*)(ob + 0)  = o0;
        *(float4*)(ob + 16) = o1;
    }
}

extern "C" void kernel_launch(void* const* d_in, const int* in_sizes, int n_in,
                              void* d_out, int out_size, void* d_ws, size_t ws_size,
                              hipStream_t stream) {
    const float* queries = (const float*)d_in[0];
    const float* keys    = (const float*)d_in[1];
    const float* values  = (const float*)d_in[2];
    const float* W_q     = (const float*)d_in[3];
    const float* W_k     = (const float*)d_in[4];
    const float* w_v     = (const float*)d_in[5];
    float* out = (float*)d_out;

    float* Eq  = (float*)d_ws;                 // [B*Q, H]      1 MB
    float* Ekt = Eq + Bn * Qn * Hh;            // [B, H, K]     1 MB
    short* Vhi = (short*)(Ekt + Bn * Kn * Hh); // frag-order    2 MB
    short* Vlo = Vhi + (size_t)Bn * Kn * Dv;   // frag-order    2 MB

    prep_kernel<<<640, 256, 0, stream>>>(queries, W_q, keys, W_k, values,
                                         Eq, Ekt, Vhi, Vlo);
    attn_kernel<<<Bn * (Qn / TQ), 512, 0, stream>>>(Eq, Ekt, Vhi, Vlo, w_v, out);
}

// Round 9
// 140.766 us; speedup vs baseline: 1.0748x; 1.0024x over previous
//
#include <hip/hip_runtime.h>

#define Bn 4
#define Qn 1024
#define Kn 1024
#define Dd 256
#define Hh 64
#define Dv 256
#define TQ 8
#define SCP 1028   // sc row stride in floats (4112 B/row = 2056 shorts)

typedef __attribute__((ext_vector_type(8))) short short8;
typedef __attribute__((ext_vector_type(4))) float floatx4;

__device__ __forceinline__ short f32_to_bf16(float x) {
    unsigned u = __float_as_uint(x);
    unsigned r = u + 0x7fffu + ((u >> 16) & 1u);   // RNE
    return (short)(r >> 16);
}
__device__ __forceinline__ float bf16_to_f32(short h) {
    return __uint_as_float(((unsigned)(unsigned short)h) << 16);
}

// Fused prep (R7 structure — known good):
//  blocks 0..511  : projections (Eq + transposed Ekt, exp-folded), 4 rows/wave
//  blocks 512..639: V -> split-bf16 MFMA-A-fragment swizzle
__global__ __launch_bounds__(256) void prep_kernel(const float* __restrict__ Xq,
                                                   const float* __restrict__ Wq,
                                                   const float* __restrict__ Xk,
                                                   const float* __restrict__ Wk,
                                                   const float* __restrict__ V,
                                                   float* __restrict__ Eq,
                                                   float* __restrict__ Ekt,
                                                   short* __restrict__ Vhi,
                                                   short* __restrict__ Vlo) {
    __shared__ float tile[32 * 261];
    int t = threadIdx.x;
    if (blockIdx.x < 512) {
        int gw = blockIdx.x * 4 + (t >> 6);
        int h = t & 63;
        int side = gw >> 10;
        int row0 = (gw & 1023) * 4;
        const float* X = side ? Xk : Xq;
        const float* W = side ? Wk : Wq;
        float acc[4] = {0.f, 0.f, 0.f, 0.f};
        for (int d4 = 0; d4 < Dd / 4; ++d4) {
            float w0 = W[(d4 * 4 + 0) * Hh + h];
            float w1 = W[(d4 * 4 + 1) * Hh + h];
            float w2 = W[(d4 * 4 + 2) * Hh + h];
            float w3 = W[(d4 * 4 + 3) * Hh + h];
            #pragma unroll
            for (int r = 0; r < 4; ++r) {
                float4 xv = ((const float4*)(X + (row0 + r) * Dd))[d4];
                acc[r] = fmaf(xv.x, w0, acc[r]);
                acc[r] = fmaf(xv.y, w1, acc[r]);
                acc[r] = fmaf(xv.z, w2, acc[r]);
                acc[r] = fmaf(xv.w, w3, acc[r]);
            }
        }
        #pragma unroll
        for (int r = 0; r < 4; ++r) {
            int row = row0 + r;
            float e = __expf(2.f * acc[r]);
            if (!side) {
                Eq[row * Hh + h] = e;
            } else {
                int b = row >> 10, k = row & 1023;
                Ekt[(b * Hh + h) * Kn + k] = e;
            }
        }
    } else {
        int blk = blockIdx.x - 512;
        int b = blk >> 5;
        int kt = blk & 31;
        const float* Vg = V + (b * Kn + kt * 32) * Dv;
        for (int i = 0; i < 8; ++i) {
            int k = i * 4 + (t >> 6);
            int n4 = (t & 63) * 4;
            float4 v = *(const float4*)(Vg + k * Dv + n4);
            tile[k * 261 + n4 + 0] = v.x;
            tile[k * 261 + n4 + 1] = v.y;
            tile[k * 261 + n4 + 2] = v.z;
            tile[k * 261 + n4 + 3] = v.w;
        }
        __syncthreads();
        int wave = t >> 6, l = t & 63;
        int n_in = l & 15, kc = l >> 4;
        for (int p = 0; p < 4; ++p) {
            int nt = wave * 4 + p;
            int n = nt * 16 + n_in;
            short8 hi, lo;
            #pragma unroll
            for (int j = 0; j < 8; ++j) {
                float x = tile[(kc * 8 + j) * 261 + n];
                short hs = f32_to_bf16(x);
                hi[j] = hs;
                lo[j] = f32_to_bf16(x - bf16_to_f32(hs));
            }
            size_t base = (((size_t)(b * 32 + kt) * 16 + nt) * 512) + (size_t)l * 8;
            *(short8*)(Vhi + base) = hi;
            *(short8*)(Vlo + base) = lo;
        }
    }
}

// score(q,k) = W_sum - 2*sum_h w_h/(Eq_h*Ek_h+1); W_sum cancels in softmax.
// Scores bounded by ||w_v||_1 (~6.4) -> NO max-subtraction needed: p = exp(-2s)
// computed inline in the score phase, converted to bf16 hi/lo and written
// straight to sc as shorts; per-q sums reduced via shuffles. Saves the min
// pass, fp32 score store+reload, separate convert pass, and 2 barriers.
// AV via mfma_f32_16x16x32_bf16 split precision. XCD swizzle: batch = XCD/2.
__global__ __launch_bounds__(512) void attn_kernel(const float* __restrict__ Eq,
                                                   const float* __restrict__ Ekt,
                                                   const short* __restrict__ Vhi,
                                                   const short* __restrict__ Vlo,
                                                   const float* __restrict__ wv,
                                                   float* __restrict__ out) {
    __shared__ __align__(16) float sc[TQ * SCP];       // 32.9 KB: P hi/lo shorts
    __shared__ __align__(16) float4 qp4[TQ * (Hh / 4)];// 2 KB
    __shared__ __align__(16) float wv_s[Hh];
    __shared__ float wsum[8 * TQ];
    __shared__ float rinv_s[TQ];

    int tid = threadIdx.x;
    int blk = blockIdx.x;
    // XCD-aware swizzle: consecutive blocks round-robin XCDs (blk%8 = XCD);
    // pin batch b to XCDs {2b, 2b+1} so each XCD's L2 holds ONE batch's
    // Ekt(1MB) + split-V(2MB) = 3MB < 4MB.
    int b = (blk & 7) >> 1;
    int tile = (blk >> 3) * 2 + (blk & 1);   // 0..127, bijective per batch
    int qbase = tile * TQ;

    const float* qrow = Eq + (b * Qn + qbase) * Hh;
    ((float*)qp4)[tid] = qrow[tid];          // 512 = TQ*Hh
    if (tid < Hh) wv_s[tid] = wv[tid];
    __syncthreads();

    // ---- score phase: thread owns k = tid + 512*j; p=exp(-2s) inline ----
    const float* kb = Ekt + b * Hh * Kn;
    float s[TQ][2];
    #pragma unroll
    for (int q = 0; q < TQ; ++q) { s[q][0] = 0.f; s[q][1] = 0.f; }

    for (int h4 = 0; h4 < Hh / 4; ++h4) {
        float4 w4 = ((const float4*)wv_s)[h4];
        const float* kh = kb + h4 * 4 * Kn;
        float e0[2], e1[2], e2[2], e3[2];
        #pragma unroll
        for (int j = 0; j < 2; ++j) {
            int k = tid + j * 512;
            e0[j] = kh[0 * Kn + k];
            e1[j] = kh[1 * Kn + k];
            e2[j] = kh[2 * Kn + k];
            e3[j] = kh[3 * Kn + k];
        }
        #pragma unroll 4
        for (int q = 0; q < TQ; ++q) {
            float4 qv = qp4[q * (Hh / 4) + h4];          // LDS b128 broadcast
            #pragma unroll
            for (int j = 0; j < 2; ++j) {
                float a  = fmaf(qv.x, e0[j], 1.f);
                float bb = fmaf(qv.y, e1[j], 1.f);
                float c  = fmaf(qv.z, e2[j], 1.f);
                float d  = fmaf(qv.w, e3[j], 1.f);
                float nab = fmaf(w4.x, bb, w4.y * a);
                float ncd = fmaf(w4.z, d, w4.w * c);
                s[q][j] = fmaf(nab, __builtin_amdgcn_rcpf(a * bb), s[q][j]);
                s[q][j] = fmaf(ncd, __builtin_amdgcn_rcpf(c * d), s[q][j]);
            }
        }
    }

    // p = exp(-2s); write bf16 hi/lo shorts straight to sc; sum per q.
    // Row q layout (shorts): hi at q*2056 + k, lo at q*2056 + 1024 + k.
    short* sp = (short*)sc;
    float part[TQ];
    #pragma unroll
    for (int q = 0; q < TQ; ++q) {
        float p0 = __expf(-2.f * s[q][0]);
        float p1 = __expf(-2.f * s[q][1]);
        part[q] = p0 + p1;
        short h0 = f32_to_bf16(p0);
        short h1 = f32_to_bf16(p1);
        sp[q * 2056 + tid] = h0;
        sp[q * 2056 + 1024 + tid] = f32_to_bf16(p0 - bf16_to_f32(h0));
        sp[q * 2056 + 512 + tid] = h1;              // k = tid+512 (hi)
        sp[q * 2056 + 1536 + tid] = f32_to_bf16(p1 - bf16_to_f32(h1));
    }

    int wave = tid >> 6, lane = tid & 63;
    #pragma unroll
    for (int q = 0; q < TQ; ++q) {
        #pragma unroll
        for (int off = 32; off >= 1; off >>= 1)
            part[q] += __shfl_xor(part[q], off, 64);
    }
    if (lane == 0) {
        #pragma unroll
        for (int q = 0; q < TQ; ++q) wsum[wave * TQ + q] = part[q];
    }
    __syncthreads();

    // wave w finalizes row q=w: sum the 8 per-wave partials
    {
        float v = (lane < 8) ? wsum[lane * TQ + wave] : 0.f;
        v += __shfl_xor(v, 4, 64);
        v += __shfl_xor(v, 2, 64);
        v += __shfl_xor(v, 1, 64);
        if (lane == 0) rinv_s[wave] = 1.f / v;
    }
    __syncthreads();

    // ---- AV via MFMA: wave owns ntiles {2w, 2w+1}; q-cols 8..15 masked ----
    int qf = lane & 15, kc = lane >> 4;
    int q8 = qf & 7;
    bool qok = qf < TQ;
    floatx4 acc0 = {0.f, 0.f, 0.f, 0.f};
    floatx4 acc1 = {0.f, 0.f, 0.f, 0.f};
    short8 z8 = (short8)(short)0;
    const char* scb = (const char*)sc;
    for (int kt = 0; kt < 32; ++kt) {
        short8 bhi = *(const short8*)(scb + q8 * 4112 + kt * 64 + kc * 16);
        short8 blo = *(const short8*)(scb + q8 * 4112 + 2048 + kt * 64 + kc * 16);
        if (!qok) { bhi = z8; blo = z8; }
        size_t base0 = (((size_t)(b * 32 + kt) * 16 + wave * 2 + 0) * 512) + (size_t)lane * 8;
        size_t base1 = (((size_t)(b * 32 + kt) * 16 + wave * 2 + 1) * 512) + (size_t)lane * 8;
        short8 a0h = *(const short8*)(Vhi + base0);
        short8 a0l = *(const short8*)(Vlo + base0);
        short8 a1h = *(const short8*)(Vhi + base1);
        short8 a1l = *(const short8*)(Vlo + base1);
        acc0 = __builtin_amdgcn_mfma_f32_16x16x32_bf16(a0h, bhi, acc0, 0, 0, 0);
        acc0 = __builtin_amdgcn_mfma_f32_16x16x32_bf16(a0l, bhi, acc0, 0, 0, 0);
        acc0 = __builtin_amdgcn_mfma_f32_16x16x32_bf16(a0h, blo, acc0, 0, 0, 0);
        acc1 = __builtin_amdgcn_mfma_f32_16x16x32_bf16(a1h, bhi, acc1, 0, 0, 0);
        acc1 = __builtin_amdgcn_mfma_f32_16x16x32_bf16(a1l, bhi, acc1, 0, 0, 0);
        acc1 = __builtin_amdgcn_mfma_f32_16x16x32_bf16(a1h, blo, acc1, 0, 0, 0);
    }
    if (qok) {
        float r = rinv_s[q8];
        float* ob = out + ((size_t)(b * Qn + qbase + q8)) * Dv + wave * 32 + kc * 4;
        float4 o0 = { acc0[0] * r, acc0[1] * r, acc0[2] * r, acc0[3] * r };
        float4 o1 = { acc1[0] * r, acc1[1] * r, acc1[2] * r, acc1[3] * r };
        *(float4*)(ob + 0)  = o0;
        *(float4*)(ob + 16) = o1;
    }
}

extern "C" void kernel_launch(void* const* d_in, const int* in_sizes, int n_in,
                              void* d_out, int out_size, void* d_ws, size_t ws_size,
                              hipStream_t stream) {
    const float* queries = (const float*)d_in[0];
    const float* keys    = (const float*)d_in[1];
    const float* values  = (const float*)d_in[2];
    const float* W_q     = (const float*)d_in[3];
    const float* W_k     = (const float*)d_in[4];
    const float* w_v     = (const float*)d_in[5];
    float* out = (float*)d_out;

    float* Eq  = (float*)d_ws;                 // [B*Q, H]      1 MB
    float* Ekt = Eq + Bn * Qn * Hh;            // [B, H, K]     1 MB
    short* Vhi = (short*)(Ekt + Bn * Kn * Hh); // frag-order    2 MB
    short* Vlo = Vhi + (size_t)Bn * Kn * Dv;   // frag-order    2 MB

    prep_kernel<<<640, 256, 0, stream>>>(queries, W_q, keys, W_k, values,
                                         Eq, Ekt, Vhi, Vlo);
    attn_kernel<<<Bn * (Qn / TQ), 512, 0, stream>>>(Eq, Ekt, Vhi, Vlo, w_v, out);
}

// Round 10
// 133.597 us; speedup vs baseline: 1.1324x; 1.0537x over previous
//
#include <hip/hip_runtime.h>

#define Bn 4
#define Qn 1024
#define Kn 1024
#define Dd 256
#define Hh 64
#define Dv 256
#define TQ 8
#define SCP 1028   // sc row stride in floats (4112 B/row = 2056 shorts)

typedef __attribute__((ext_vector_type(8))) short short8;
typedef __attribute__((ext_vector_type(4))) float floatx4;

__device__ __forceinline__ short f32_to_bf16(float x) {
    unsigned u = __float_as_uint(x);
    unsigned r = u + 0x7fffu + ((u >> 16) & 1u);   // RNE
    return (short)(r >> 16);
}
__device__ __forceinline__ float bf16_to_f32(short h) {
    return __uint_as_float(((unsigned)(unsigned short)h) << 16);
}
__device__ __forceinline__ unsigned pack2(float lo_val, float hi_val) {
    return (unsigned)(unsigned short)f32_to_bf16(lo_val)
         | ((unsigned)(unsigned short)f32_to_bf16(hi_val) << 16);
}

// Fused prep (unchanged, known good):
//  blocks 0..511  : projections (Eq + transposed Ekt, exp-folded), 4 rows/wave
//  blocks 512..639: V -> split-bf16 MFMA-A-fragment swizzle
__global__ __launch_bounds__(256) void prep_kernel(const float* __restrict__ Xq,
                                                   const float* __restrict__ Wq,
                                                   const float* __restrict__ Xk,
                                                   const float* __restrict__ Wk,
                                                   const float* __restrict__ V,
                                                   float* __restrict__ Eq,
                                                   float* __restrict__ Ekt,
                                                   short* __restrict__ Vhi,
                                                   short* __restrict__ Vlo) {
    __shared__ float tile[32 * 261];
    int t = threadIdx.x;
    if (blockIdx.x < 512) {
        int gw = blockIdx.x * 4 + (t >> 6);
        int h = t & 63;
        int side = gw >> 10;
        int row0 = (gw & 1023) * 4;
        const float* X = side ? Xk : Xq;
        const float* W = side ? Wk : Wq;
        float acc[4] = {0.f, 0.f, 0.f, 0.f};
        for (int d4 = 0; d4 < Dd / 4; ++d4) {
            float w0 = W[(d4 * 4 + 0) * Hh + h];
            float w1 = W[(d4 * 4 + 1) * Hh + h];
            float w2 = W[(d4 * 4 + 2) * Hh + h];
            float w3 = W[(d4 * 4 + 3) * Hh + h];
            #pragma unroll
            for (int r = 0; r < 4; ++r) {
                float4 xv = ((const float4*)(X + (row0 + r) * Dd))[d4];
                acc[r] = fmaf(xv.x, w0, acc[r]);
                acc[r] = fmaf(xv.y, w1, acc[r]);
                acc[r] = fmaf(xv.z, w2, acc[r]);
                acc[r] = fmaf(xv.w, w3, acc[r]);
            }
        }
        #pragma unroll
        for (int r = 0; r < 4; ++r) {
            int row = row0 + r;
            float e = __expf(2.f * acc[r]);
            if (!side) {
                Eq[row * Hh + h] = e;
            } else {
                int b = row >> 10, k = row & 1023;
                Ekt[(b * Hh + h) * Kn + k] = e;
            }
        }
    } else {
        int blk = blockIdx.x - 512;
        int b = blk >> 5;
        int kt = blk & 31;
        const float* Vg = V + (b * Kn + kt * 32) * Dv;
        for (int i = 0; i < 8; ++i) {
            int k = i * 4 + (t >> 6);
            int n4 = (t & 63) * 4;
            float4 v = *(const float4*)(Vg + k * Dv + n4);
            tile[k * 261 + n4 + 0] = v.x;
            tile[k * 261 + n4 + 1] = v.y;
            tile[k * 261 + n4 + 2] = v.z;
            tile[k * 261 + n4 + 3] = v.w;
        }
        __syncthreads();
        int wave = t >> 6, l = t & 63;
        int n_in = l & 15, kc = l >> 4;
        for (int p = 0; p < 4; ++p) {
            int nt = wave * 4 + p;
            int n = nt * 16 + n_in;
            short8 hi, lo;
            #pragma unroll
            for (int j = 0; j < 8; ++j) {
                float x = tile[(kc * 8 + j) * 261 + n];
                short hs = f32_to_bf16(x);
                hi[j] = hs;
                lo[j] = f32_to_bf16(x - bf16_to_f32(hs));
            }
            size_t base = (((size_t)(b * 32 + kt) * 16 + nt) * 512) + (size_t)l * 8;
            *(short8*)(Vhi + base) = hi;
            *(short8*)(Vlo + base) = lo;
        }
    }
}

// score(q,k) = W_sum - 2*sum_h w_h/(Eq_h*Ek_h+1); W_sum cancels in softmax.
// Scores bounded by ||w_v||_1 -> no max-subtraction: p = exp(-2s) fused into
// score phase, bf16 hi/lo pairs packed to single b32 LDS writes.
// __launch_bounds__(512,4): true occupancy is LDS-bound at 2 blocks/CU =
// 4 waves/SIMD -> give the allocator the full 128-VGPR budget (R9's 32-VGPR
// allocation serialized the score loop on load latency; duration was pinned
// at 59.5us across 4 variants while VALUBusy fell - classic ILP starvation).
// Thread owns k = {2*tid, 2*tid+1}: float2 Ekt loads, explicit e/en prefetch.
__global__ __launch_bounds__(512, 4) void attn_kernel(const float* __restrict__ Eq,
                                                      const float* __restrict__ Ekt,
                                                      const short* __restrict__ Vhi,
                                                      const short* __restrict__ Vlo,
                                                      const float* __restrict__ wv,
                                                      float* __restrict__ out) {
    __shared__ __align__(16) float sc[TQ * SCP];       // 32.9 KB: P hi/lo shorts
    __shared__ __align__(16) float4 qp4[TQ * (Hh / 4)];// 2 KB
    __shared__ __align__(16) float wv_s[Hh];
    __shared__ float wsum[8 * TQ];
    __shared__ float rinv_s[TQ];

    int tid = threadIdx.x;
    int blk = blockIdx.x;
    // XCD-aware swizzle: blk%8 = XCD; batch b pinned to XCDs {2b,2b+1} so one
    // XCD's L2 holds one batch's Ekt(1MB)+split-V(2MB) = 3MB < 4MB.
    int b = (blk & 7) >> 1;
    int tile = (blk >> 3) * 2 + (blk & 1);   // 0..127, bijective per batch
    int qbase = tile * TQ;

    const float* qrow = Eq + (b * Qn + qbase) * Hh;
    ((float*)qp4)[tid] = qrow[tid];          // 512 = TQ*Hh
    if (tid < Hh) wv_s[tid] = wv[tid];
    __syncthreads();

    // ---- score phase: thread owns k = 2*tid, 2*tid+1 ----
    const float2* kb2 = (const float2*)(Ekt + b * Hh * Kn);
    float s[TQ][2];
    #pragma unroll
    for (int q = 0; q < TQ; ++q) { s[q][0] = 0.f; s[q][1] = 0.f; }

    float2 e0 = kb2[0 * (Kn / 2) + tid];
    float2 e1 = kb2[1 * (Kn / 2) + tid];
    float2 e2 = kb2[2 * (Kn / 2) + tid];
    float2 e3 = kb2[3 * (Kn / 2) + tid];
    for (int h4 = 0; h4 < Hh / 4; ++h4) {
        float2 n0, n1, n2, n3;
        if (h4 < Hh / 4 - 1) {                 // prefetch next iteration
            const float2* kn = kb2 + (h4 + 1) * 4 * (Kn / 2);
            n0 = kn[0 * (Kn / 2) + tid];
            n1 = kn[1 * (Kn / 2) + tid];
            n2 = kn[2 * (Kn / 2) + tid];
            n3 = kn[3 * (Kn / 2) + tid];
        }
        float4 w4 = ((const float4*)wv_s)[h4];
        #pragma unroll
        for (int q = 0; q < TQ; ++q) {
            float4 qv = qp4[q * (Hh / 4) + h4];          // LDS b128 broadcast
            {   // k = 2*tid
                float a  = fmaf(qv.x, e0.x, 1.f);
                float bb = fmaf(qv.y, e1.x, 1.f);
                float c  = fmaf(qv.z, e2.x, 1.f);
                float d  = fmaf(qv.w, e3.x, 1.f);
                float nab = fmaf(w4.x, bb, w4.y * a);
                float ncd = fmaf(w4.z, d, w4.w * c);
                s[q][0] = fmaf(nab, __builtin_amdgcn_rcpf(a * bb), s[q][0]);
                s[q][0] = fmaf(ncd, __builtin_amdgcn_rcpf(c * d), s[q][0]);
            }
            {   // k = 2*tid+1
                float a  = fmaf(qv.x, e0.y, 1.f);
                float bb = fmaf(qv.y, e1.y, 1.f);
                float c  = fmaf(qv.z, e2.y, 1.f);
                float d  = fmaf(qv.w, e3.y, 1.f);
                float nab = fmaf(w4.x, bb, w4.y * a);
                float ncd = fmaf(w4.z, d, w4.w * c);
                s[q][1] = fmaf(nab, __builtin_amdgcn_rcpf(a * bb), s[q][1]);
                s[q][1] = fmaf(ncd, __builtin_amdgcn_rcpf(c * d), s[q][1]);
            }
        }
        e0 = n0; e1 = n1; e2 = n2; e3 = n3;
    }

    // p = exp(-2s); pack bf16 pairs -> one b32 write each for hi and lo.
    // Row q shorts: hi at q*2056 + k, lo at q*2056 + 1024 + k (k=2tid,2tid+1
    // adjacent -> uint idx q*1028 + tid and q*1028 + 512 + tid).
    unsigned* su = (unsigned*)sc;
    float part[TQ];
    #pragma unroll
    for (int q = 0; q < TQ; ++q) {
        float p0 = __expf(-2.f * s[q][0]);
        float p1 = __expf(-2.f * s[q][1]);
        part[q] = p0 + p1;
        float r0 = p0 - bf16_to_f32(f32_to_bf16(p0));
        float r1 = p1 - bf16_to_f32(f32_to_bf16(p1));
        su[q * 1028 + tid] = pack2(p0, p1);
        su[q * 1028 + 512 + tid] = pack2(r0, r1);
    }

    int wave = tid >> 6, lane = tid & 63;
    #pragma unroll
    for (int q = 0; q < TQ; ++q) {
        #pragma unroll
        for (int off = 32; off >= 1; off >>= 1)
            part[q] += __shfl_xor(part[q], off, 64);
    }
    if (lane == 0) {
        #pragma unroll
        for (int q = 0; q < TQ; ++q) wsum[wave * TQ + q] = part[q];
    }
    __syncthreads();

    {   // wave w finalizes row q=w
        float v = (lane < 8) ? wsum[lane * TQ + wave] : 0.f;
        v += __shfl_xor(v, 4, 64);
        v += __shfl_xor(v, 2, 64);
        v += __shfl_xor(v, 1, 64);
        if (lane == 0) rinv_s[wave] = 1.f / v;
    }
    __syncthreads();

    // ---- AV via MFMA: wave owns ntiles {2w, 2w+1}; q-cols 8..15 masked ----
    int qf = lane & 15, kc = lane >> 4;
    int q8 = qf & 7;
    bool qok = qf < TQ;
    floatx4 acc0 = {0.f, 0.f, 0.f, 0.f};
    floatx4 acc1 = {0.f, 0.f, 0.f, 0.f};
    short8 z8 = (short8)(short)0;
    const char* scb = (const char*)sc;
    for (int kt = 0; kt < 32; ++kt) {
        short8 bhi = *(const short8*)(scb + q8 * 4112 + kt * 64 + kc * 16);
        short8 blo = *(const short8*)(scb + q8 * 4112 + 2048 + kt * 64 + kc * 16);
        if (!qok) { bhi = z8; blo = z8; }
        size_t base0 = (((size_t)(b * 32 + kt) * 16 + wave * 2 + 0) * 512) + (size_t)lane * 8;
        size_t base1 = (((size_t)(b * 32 + kt) * 16 + wave * 2 + 1) * 512) + (size_t)lane * 8;
        short8 a0h = *(const short8*)(Vhi + base0);
        short8 a0l = *(const short8*)(Vlo + base0);
        short8 a1h = *(const short8*)(Vhi + base1);
        short8 a1l = *(const short8*)(Vlo + base1);
        acc0 = __builtin_amdgcn_mfma_f32_16x16x32_bf16(a0h, bhi, acc0, 0, 0, 0);
        acc0 = __builtin_amdgcn_mfma_f32_16x16x32_bf16(a0l, bhi, acc0, 0, 0, 0);
        acc0 = __builtin_amdgcn_mfma_f32_16x16x32_bf16(a0h, blo, acc0, 0, 0, 0);
        acc1 = __builtin_amdgcn_mfma_f32_16x16x32_bf16(a1h, bhi, acc1, 0, 0, 0);
        acc1 = __builtin_amdgcn_mfma_f32_16x16x32_bf16(a1l, bhi, acc1, 0, 0, 0);
        acc1 = __builtin_amdgcn_mfma_f32_16x16x32_bf16(a1h, blo, acc1, 0, 0, 0);
    }
    if (qok) {
        float r = rinv_s[q8];
        float* ob = out + ((size_t)(b * Qn + qbase + q8)) * Dv + wave * 32 + kc * 4;
        float4 o0 = { acc0[0] * r, acc0[1] * r, acc0[2] * r, acc0[3] * r };
        float4 o1 = { acc1[0] * r, acc1[1] * r, acc1[2] * r, acc1[3] * r };
        *(float4*)(ob + 0)  = o0;
        *(float4*)(ob + 16) = o1;
    }
}

extern "C" void kernel_launch(void* const* d_in, const int* in_sizes, int n_in,
                              void* d_out, int out_size, void* d_ws, size_t ws_size,
                              hipStream_t stream) {
    const float* queries = (const float*)d_in[0];
    const float* keys    = (const float*)d_in[1];
    const float* values  = (const float*)d_in[2];
    const float* W_q     = (const float*)d_in[3];
    const float* W_k     = (const float*)d_in[4];
    const float* w_v     = (const float*)d_in[5];
    float* out = (float*)d_out;

    float* Eq  = (float*)d_ws;                 // [B*Q, H]      1 MB
    float* Ekt = Eq + Bn * Qn * Hh;            // [B, H, K]     1 MB
    short* Vhi = (short*)(Ekt + Bn * Kn * Hh); // frag-order    2 MB
    short* Vlo = Vhi + (size_t)Bn * Kn * Dv;   // frag-order    2 MB

    prep_kernel<<<640, 256, 0, stream>>>(queries, W_q, keys, W_k, values,
                                         Eq, Ekt, Vhi, Vlo);
    attn_kernel<<<Bn * (Qn / TQ), 512, 0, stream>>>(Eq, Ekt, Vhi, Vlo, w_v, out);
}

// Round 11
// 129.533 us; speedup vs baseline: 1.1680x; 1.0314x over previous
//
#include <hip/hip_runtime.h>

#define Bn 4
#define Qn 1024
#define Kn 1024
#define Dd 256
#define Hh 64
#define Dv 256
#define TQ 16

typedef __attribute__((ext_vector_type(8))) short short8;
typedef __attribute__((ext_vector_type(4))) float floatx4;

__device__ __forceinline__ short f32_to_bf16(float x) {
    unsigned u = __float_as_uint(x);
    unsigned r = u + 0x7fffu + ((u >> 16) & 1u);   // RNE
    return (short)(r >> 16);
}
__device__ __forceinline__ float bf16_to_f32(short h) {
    return __uint_as_float(((unsigned)(unsigned short)h) << 16);
}

// Fused prep (unchanged from R10, known good):
//  blocks 0..511  : projections (Eq + transposed Ekt, exp-folded), 4 rows/wave
//  blocks 512..639: V -> split-bf16 MFMA-A-fragment swizzle
__global__ __launch_bounds__(256) void prep_kernel(const float* __restrict__ Xq,
                                                   const float* __restrict__ Wq,
                                                   const float* __restrict__ Xk,
                                                   const float* __restrict__ Wk,
                                                   const float* __restrict__ V,
                                                   float* __restrict__ Eq,
                                                   float* __restrict__ Ekt,
                                                   short* __restrict__ Vhi,
                                                   short* __restrict__ Vlo) {
    __shared__ float tile[32 * 261];
    int t = threadIdx.x;
    if (blockIdx.x < 512) {
        int gw = blockIdx.x * 4 + (t >> 6);
        int h = t & 63;
        int side = gw >> 10;
        int row0 = (gw & 1023) * 4;
        const float* X = side ? Xk : Xq;
        const float* W = side ? Wk : Wq;
        float acc[4] = {0.f, 0.f, 0.f, 0.f};
        for (int d4 = 0; d4 < Dd / 4; ++d4) {
            float w0 = W[(d4 * 4 + 0) * Hh + h];
            float w1 = W[(d4 * 4 + 1) * Hh + h];
            float w2 = W[(d4 * 4 + 2) * Hh + h];
            float w3 = W[(d4 * 4 + 3) * Hh + h];
            #pragma unroll
            for (int r = 0; r < 4; ++r) {
                float4 xv = ((const float4*)(X + (row0 + r) * Dd))[d4];
                acc[r] = fmaf(xv.x, w0, acc[r]);
                acc[r] = fmaf(xv.y, w1, acc[r]);
                acc[r] = fmaf(xv.z, w2, acc[r]);
                acc[r] = fmaf(xv.w, w3, acc[r]);
            }
        }
        #pragma unroll
        for (int r = 0; r < 4; ++r) {
            int row = row0 + r;
            float e = __expf(2.f * acc[r]);
            if (!side) {
                Eq[row * Hh + h] = e;
            } else {
                int b = row >> 10, k = row & 1023;
                Ekt[(b * Hh + h) * Kn + k] = e;
            }
        }
    } else {
        int blk = blockIdx.x - 512;
        int b = blk >> 5;
        int kt = blk & 31;
        const float* Vg = V + (b * Kn + kt * 32) * Dv;
        for (int i = 0; i < 8; ++i) {
            int k = i * 4 + (t >> 6);
            int n4 = (t & 63) * 4;
            float4 v = *(const float4*)(Vg + k * Dv + n4);
            tile[k * 261 + n4 + 0] = v.x;
            tile[k * 261 + n4 + 1] = v.y;
            tile[k * 261 + n4 + 2] = v.z;
            tile[k * 261 + n4 + 3] = v.w;
        }
        __syncthreads();
        int wave = t >> 6, l = t & 63;
        int n_in = l & 15, kc = l >> 4;
        for (int p = 0; p < 4; ++p) {
            int nt = wave * 4 + p;
            int n = nt * 16 + n_in;
            short8 hi, lo;
            #pragma unroll
            for (int j = 0; j < 8; ++j) {
                float x = tile[(kc * 8 + j) * 261 + n];
                short hs = f32_to_bf16(x);
                hi[j] = hs;
                lo[j] = f32_to_bf16(x - bf16_to_f32(hs));
            }
            size_t base = (((size_t)(b * 32 + kt) * 16 + nt) * 512) + (size_t)l * 8;
            *(short8*)(Vhi + base) = hi;
            *(short8*)(Vlo + base) = lo;
        }
    }
}

// score(q,k) = W_sum - 2*sum_h w_h/(Eq_h*Ek_h+1); W_sum cancels in softmax.
// Bounded scores (||w_v||_1 ~ 6.4) -> no max-subtraction; p = exp(-2s) fused.
// TQ=16: every MFMA B-column live (R10 masked half) and V L2 traffic halves.
// 1024 threads + __launch_bounds__(1024,4): 16 waves/CU, 128-VGPR budget
// (R6's TQ=16 failure was default-bounds VGPR starvation at 20 regs).
// Score loop uses NO LDS: qv/w4 are wave-uniform -> scalar (s_load) reads
// from global, leaving the LDS pipe free; P hi/lo written once as b16.
__global__ __launch_bounds__(1024, 4) void attn_kernel(const float* __restrict__ Eq,
                                                       const float* __restrict__ Ekt,
                                                       const short* __restrict__ Vhi,
                                                       const short* __restrict__ Vlo,
                                                       const float* __restrict__ wv,
                                                       float* __restrict__ out) {
    __shared__ __align__(16) unsigned sc[TQ * 1028];   // 65.8 KB: P hi/lo shorts
    __shared__ float wsum[16 * TQ];
    __shared__ float rinv_s[TQ];

    int tid = threadIdx.x;
    int blk = blockIdx.x;
    // XCD swizzle: blk%8 = XCD; batch b pinned to XCDs {2b,2b+1} (3 MB/XCD-pair).
    int b = (blk & 7) >> 1;
    int tile = (blk >> 3) * 2 + (blk & 1);   // 0..63, bijective per batch
    int qbase = tile * TQ;

    // ---- score phase: thread owns k = tid ----
    const float* kb = Ekt + b * Hh * Kn;
    const float* qp = Eq + (size_t)(b * Qn + qbase) * Hh;   // wave-uniform base
    float s[TQ];
    #pragma unroll
    for (int q = 0; q < TQ; ++q) s[q] = 0.f;

    float e0 = kb[0 * Kn + tid];
    float e1 = kb[1 * Kn + tid];
    float e2 = kb[2 * Kn + tid];
    float e3 = kb[3 * Kn + tid];
    for (int h4 = 0; h4 < Hh / 4; ++h4) {
        float n0, n1, n2, n3;
        if (h4 < Hh / 4 - 1) {                 // prefetch next iteration
            const float* kn = kb + (h4 + 1) * 4 * Kn;
            n0 = kn[0 * Kn + tid];
            n1 = kn[1 * Kn + tid];
            n2 = kn[2 * Kn + tid];
            n3 = kn[3 * Kn + tid];
        }
        float4 w4 = ((const float4*)wv)[h4];            // uniform -> s_load
        #pragma unroll
        for (int q = 0; q < TQ; ++q) {
            float4 qv = *(const float4*)(qp + q * Hh + h4 * 4);  // uniform -> s_load
            float a  = fmaf(qv.x, e0, 1.f);
            float bb = fmaf(qv.y, e1, 1.f);
            float c  = fmaf(qv.z, e2, 1.f);
            float d  = fmaf(qv.w, e3, 1.f);
            float nab = fmaf(w4.x, bb, w4.y * a);
            float ncd = fmaf(w4.z, d, w4.w * c);
            s[q] = fmaf(nab, __builtin_amdgcn_rcpf(a * bb), s[q]);
            s[q] = fmaf(ncd, __builtin_amdgcn_rcpf(c * d), s[q]);
        }
        e0 = n0; e1 = n1; e2 = n2; e3 = n3;
    }

    // p = exp(-2s); write bf16 hi/lo b16; per-q wave partials.
    // Row q shorts: hi at q*2056 + k, lo at q*2056 + 1024 + k.
    unsigned short* sp = (unsigned short*)sc;
    float part[TQ];
    #pragma unroll
    for (int q = 0; q < TQ; ++q) {
        float p = __expf(-2.f * s[q]);
        part[q] = p;
        short hs = f32_to_bf16(p);
        sp[q * 2056 + tid] = (unsigned short)hs;
        sp[q * 2056 + 1024 + tid] = (unsigned short)f32_to_bf16(p - bf16_to_f32(hs));
    }

    int wave = tid >> 6, lane = tid & 63;
    #pragma unroll
    for (int q = 0; q < TQ; ++q) {
        #pragma unroll
        for (int off = 32; off >= 1; off >>= 1)
            part[q] += __shfl_xor(part[q], off, 64);
    }
    if (lane == 0) {
        #pragma unroll
        for (int q = 0; q < TQ; ++q) wsum[wave * TQ + q] = part[q];
    }
    __syncthreads();

    {   // wave w finalizes row q=w: sum 16 per-wave partials
        float v = (lane < 16) ? wsum[lane * TQ + wave] : 0.f;
        v += __shfl_xor(v, 8, 64);
        v += __shfl_xor(v, 4, 64);
        v += __shfl_xor(v, 2, 64);
        v += __shfl_xor(v, 1, 64);
        if (lane == 0) rinv_s[wave] = 1.f / v;
    }
    __syncthreads();

    // ---- AV via MFMA: wave owns ntile = wave; all 16 q-cols live ----
    int qf = lane & 15, kc = lane >> 4;
    floatx4 acc = {0.f, 0.f, 0.f, 0.f};
    const char* scb = (const char*)sc;
    for (int kt = 0; kt < 32; ++kt) {
        short8 bhi = *(const short8*)(scb + qf * 4112 + kt * 64 + kc * 16);
        short8 blo = *(const short8*)(scb + qf * 4112 + 2048 + kt * 64 + kc * 16);
        size_t base = (((size_t)(b * 32 + kt) * 16 + wave) * 512) + (size_t)lane * 8;
        short8 ah = *(const short8*)(Vhi + base);
        short8 al = *(const short8*)(Vlo + base);
        acc = __builtin_amdgcn_mfma_f32_16x16x32_bf16(ah, bhi, acc, 0, 0, 0);
        acc = __builtin_amdgcn_mfma_f32_16x16x32_bf16(al, bhi, acc, 0, 0, 0);
        acc = __builtin_amdgcn_mfma_f32_16x16x32_bf16(ah, blo, acc, 0, 0, 0);
    }
    {
        float r = rinv_s[qf];
        float* ob = out + ((size_t)(b * Qn + qbase + qf)) * Dv + wave * 16 + kc * 4;
        float4 o = { acc[0] * r, acc[1] * r, acc[2] * r, acc[3] * r };
        *(float4*)ob = o;
    }
}

extern "C" void kernel_launch(void* const* d_in, const int* in_sizes, int n_in,
                              void* d_out, int out_size, void* d_ws, size_t ws_size,
                              hipStream_t stream) {
    const float* queries = (const float*)d_in[0];
    const float* keys    = (const float*)d_in[1];
    const float* values  = (const float*)d_in[2];
    const float* W_q     = (const float*)d_in[3];
    const float* W_k     = (const float*)d_in[4];
    const float* w_v     = (const float*)d_in[5];
    float* out = (float*)d_out;

    float* Eq  = (float*)d_ws;                 // [B*Q, H]      1 MB
    float* Ekt = Eq + Bn * Qn * Hh;            // [B, H, K]     1 MB
    short* Vhi = (short*)(Ekt + Bn * Kn * Hh); // frag-order    2 MB
    short* Vlo = Vhi + (size_t)Bn * Kn * Dv;   // frag-order    2 MB

    prep_kernel<<<640, 256, 0, stream>>>(queries, W_q, keys, W_k, values,
                                         Eq, Ekt, Vhi, Vlo);
    attn_kernel<<<Bn * (Qn / TQ), 1024, 0, stream>>>(Eq, Ekt, Vhi, Vlo, w_v, out);
}